// Round 11
// baseline (255.597 us; speedup 1.0000x reference)
//
#include <hip/hip_runtime.h>
#include <hip/hip_bf16.h>
#include <math.h>

// Problem dims (fixed by setup_inputs)
#define E_   8
#define H_   768
#define I_   3072
#define T_   2048
#define NTOK (E_ * T_)

typedef __attribute__((ext_vector_type(8))) short bf16x8;   // 8 bf16 = 4 VGPRs
typedef __attribute__((ext_vector_type(4))) float f32x4;    // MFMA accum

typedef __attribute__((address_space(3))) void lds_void;
typedef const __attribute__((address_space(1))) void gl_void;

__device__ __forceinline__ void gload16(const void* g, void* l) {
  // 16B async global->LDS. LDS dest is wave-uniform base + lane*16.
  __builtin_amdgcn_global_load_lds((gl_void*)g, (lds_void*)l, 16, 0, 0);
}

// Compiler-only fence (0 instructions) + raw HW barrier. NOT __syncthreads():
// that would emit s_waitcnt vmcnt(0) and drain the prefetch pipeline (T4).
#define FENCE() asm volatile("" ::: "memory")
#define BAR()                         \
  do {                                \
    FENCE();                          \
    __builtin_amdgcn_s_barrier();     \
    FENCE();                          \
  } while (0)
#define VMWAIT(n) asm volatile("s_waitcnt vmcnt(" #n ")" ::: "memory")

#define MFMA16(a, b, c) __builtin_amdgcn_mfma_f32_16x16x32_bf16(a, b, c, 0, 0, 0)

// Fast GELU: v * sigmoid(1.5957691*(v + 0.044715 v^3)); |err| ~3e-4 << bf16
// storage error of the intermediate. (Round-2 verified, absmax 0.031.)
__device__ __forceinline__ float gelu_fast(float v) {
  float inner = v * fmaf(v * v, 0.044715f, 1.0f);
  float e = __builtin_amdgcn_exp2f(inner * -2.3022082f);
  return v * __builtin_amdgcn_rcpf(1.0f + e);
}

// ---------------------------------------------------------------------------
// Fused prep kernel (round-9, frozen): one launch does
//   blocks [0, 12288)        : x fp32 -> x_bf bf16 (float4 / ushort4)
//   blocks [12288, 16896)    : w1 [E][H][I] -> w1t [E][I][H] bf16
//   blocks [16896, 21504)    : w2 [E][I][H] -> w2t [E][H][I] bf16
// ---------------------------------------------------------------------------
#define CVT_BLOCKS 12288         // NTOK*H / (256*4)
#define WT_BLOCKS  4608          // (I/64)*(H/64)*E = 48*12*8

__global__ __launch_bounds__(256) void prep_kernel(
    const float* __restrict__ x, __hip_bfloat16* __restrict__ x_bf,
    const float* __restrict__ w1, __hip_bfloat16* __restrict__ w1t,
    const float* __restrict__ w2, __hip_bfloat16* __restrict__ w2t) {
  __shared__ __hip_bfloat16 tile[64][66];
  int b = blockIdx.x;

  if (b < CVT_BLOCKS) {  // ---- cvt branch
    int i = (b * 256 + threadIdx.x) * 4;
    float4 v = *(const float4*)(x + i);
    __align__(8) __hip_bfloat16 t[4];
    t[0] = __float2bfloat16(v.x);
    t[1] = __float2bfloat16(v.y);
    t[2] = __float2bfloat16(v.z);
    t[3] = __float2bfloat16(v.w);
    *(ushort4*)(x_bf + i) = *(const ushort4*)t;
    return;
  }

  // ---- transpose branches: [E][R][C] fp32 -> [E][C][R] bf16
  const float* src;
  __hip_bfloat16* dst;
  int R, C, c0, r0;
  if (b < CVT_BLOCKS + WT_BLOCKS) {
    int t = b - CVT_BLOCKS;
    int e = t / 576, rem = t % 576;       // 576 = (I/64)*(H/64)
    R = H_; C = I_;                       // src w1 [H][I]
    c0 = (rem % 48) * 64;
    r0 = (rem / 48) * 64;
    src = w1 + (size_t)e * R * C;
    dst = w1t + (size_t)e * R * C;
  } else {
    int t = b - (CVT_BLOCKS + WT_BLOCKS);
    int e = t / 576, rem = t % 576;
    R = I_; C = H_;                       // src w2 [I][H]
    c0 = (rem % 12) * 64;
    r0 = (rem / 12) * 64;
    src = w2 + (size_t)e * R * C;
    dst = w2t + (size_t)e * R * C;
  }

  int tx = threadIdx.x & 31;  // col-pair index (2 cols/thread)
  int ty = threadIdx.x >> 5;  // 8 rows/pass
#pragma unroll
  for (int r = ty; r < 64; r += 8) {
    float2 v = *(const float2*)&src[(size_t)(r0 + r) * C + c0 + 2 * tx];
    __hip_bfloat16 b0 = __float2bfloat16(v.x);
    __hip_bfloat16 b1 = __float2bfloat16(v.y);
    ushort2 w;
    w.x = *(const ushort*)&b0;
    w.y = *(const ushort*)&b1;
    *(ushort2*)&tile[r][2 * tx] = w;
  }
  __syncthreads();
#pragma unroll
  for (int rr = ty; rr < 64; rr += 8) {
    ushort2 v;
    v.x = *(const ushort*)&tile[2 * tx][rr];
    v.y = *(const ushort*)&tile[2 * tx + 1][rr];
    *(ushort2*)&dst[(size_t)(c0 + rr) * R + r0 + 2 * tx] = v;
  }
}

// ---------------------------------------------------------------------------
// Grouped GEMM, round-11 (GEMM1): 256x256 tile, BK=64, 1024 thr = 16 waves
// (2M x 8N), per-wave 128x32 out -> acc = 64 f32/lane -> 4 waves/SIMD
// (round-10 lesson: occupancy helps [GEMM2 -15% at 3/SIMD] but narrow BN
// hurts short-K GEMM1 [FETCH +20%, +33% block prologues]. This config gets
// 4/SIMD at BN=256: FETCH back to ~72GB, grid 768, per-CU per-tile LDS/MFMA
// totals identical to the round-5 shape). LDS 128 KiB -> 1 block/CU.
//
// 2-phase merged schedule (frozen since r5). Staging fully uniform at 1024
// thr: A-half = 1 load/thread, B = 2 loads/thread. Per-thread FIFO ledger
// (stage order per tile: Ph0 issues A0',B'; Ph1 issues A1'):
//   entering Ph0: outstanding = [A0,B0,B1,A1] = 4
//   Ph0: VMWAIT(1) lands A0,B (1-tile slack); after stages: [A1,A0',B0',B1']
//   Ph1: VMWAIT(3) lands A1; after stage: [A0',B0',B1',A1'] (invariant)
//   Peeled: VMWAIT(1) / VMWAIT(0).
// WAR safety (same argument as r5-r10): a wave passes Ph0's BAR only after
// its previous-tile MFMAs issued, which required lgkmcnt drain of its
// buf-p^1 ds_reads; stages into p^1 are issued after that BAR.
// T2 swizzle: LDS linear (gload_lds), global source col-group pre-swizzled
// cg = c8 ^ (lr&7); reads XOR the same (bank conflicts measured 0).
// T1 XCD swizzle: grid % 8 == 0.
// ---------------------------------------------------------------------------
template <int K, int N, bool GELU>
__global__ __launch_bounds__(1024, 4) void gemm16w_kernel(
    const __hip_bfloat16* __restrict__ A,
    const __hip_bfloat16* __restrict__ B,
    const float* __restrict__ bias,
    __hip_bfloat16* __restrict__ out) {
  constexpr int BN = 256;
  constexpr int MT = T_ / 256;
  constexpr int NT = N / BN;
  constexpr int KT = K / 64;

  __shared__ __hip_bfloat16 sA[2][2][128][64];  // 65536 B
  __shared__ __hip_bfloat16 sB[2][BN][64];      // 65536 B

  // T1: bijective XCD swizzle (gridDim.x % 8 == 0).
  int nwg = gridDim.x;
  int b0  = blockIdx.x;
  int bid = (b0 & 7) * (nwg >> 3) + (b0 >> 3);

  int e   = bid / (MT * NT);
  int rr_ = bid % (MT * NT);
  int bm  = rr_ / NT;
  int bn  = rr_ % NT;

  const __hip_bfloat16* Ae = A + (size_t)e * T_ * K + (size_t)bm * 256 * K;
  const __hip_bfloat16* Be = B + (size_t)e * N  * K + (size_t)bn * BN * K;

  int tid  = threadIdx.x;
  int lane = tid & 63;
  int wid  = tid >> 6;      // 0..15
  int wr   = wid >> 3;      // 0..1 (M)
  int wc   = wid & 7;       // 0..7 (N)
  int l15  = lane & 15;
  int l16h = lane >> 4;     // 0..3

  // --- A staging offsets: 1 load/thread per half. idx = tid (0..1023):
  // lr = tid>>3 in [0,128), c8 = tid&7; T2 pre-swizzled source col-group.
  int lr0 = tid >> 3, c80 = tid & 7, cg0 = c80 ^ (lr0 & 7);
  int rA0 = ((lr0 >> 6) << 7) | (lr0 & 63);  // + h*64 -> global row
  const size_t oA0 = (size_t)rA0 * K + cg0 * 8;
  const size_t HOFF = (size_t)64 * K;
  // --- B staging offsets: 2 loads/thread (2048 = 2*1024 groups)
  size_t oB[2];
  int    dB[2];
#pragma unroll
  for (int q = 0; q < 2; ++q) {
    int idx = q * 1024 + tid;
    int lr = idx >> 3, c8 = idx & 7;       // lr in [0,256)
    int cg = c8 ^ (lr & 7);
    oB[q] = (size_t)lr * K + cg * 8;
    dB[q] = lr * 64 + c8 * 8;
  }

  auto stageA = [&](int buf, int h, int kt) {
    const __hip_bfloat16* g = Ae + (size_t)kt * 64 + (size_t)h * HOFF;
    gload16(g + oA0, &sA[buf][h][lr0][c80 * 8]);
  };
  auto stageB = [&](int buf, int kt) {
    const __hip_bfloat16* g = Be + (size_t)kt * 64;
    __hip_bfloat16* l = &sB[buf][0][0];
    gload16(g + oB[0], l + dB[0]);
    gload16(g + oB[1], l + dB[1]);
  };

  // --- fragment-read geometry (T2 read-side XOR)
  int laBase = wr * 64 + l15;   // + mf*16, within A-half (local rows)
  int lbBase = wc * 32 + l15;   // + nf*16 (rows of sB)
  int s7   = l15 & 7;
  int cgr0 = ((0 | l16h) ^ s7) * 8;  // ks=0 element offset
  int cgr1 = ((4 | l16h) ^ s7) * 8;  // ks=1

  f32x4 acc[8][2] = {};  // [mh*4+mf][nf]
  bf16x8 af[4][2], bfv[2][2];

  // ---- prologue: stage tile 0 in FIFO order A0, B, A1.
  stageA(0, 0, 0);
  stageB(0, 0);
  stageA(0, 1, 0);

  auto ktile = [&](int kt, int p, bool pf) {
    // ======== Ph0: quadrants (0,*). Needs A0 + all B. ========
    VMWAIT(1);  // lands A0,B of kt (leaves A1)
    BAR();
#pragma unroll
    for (int mf = 0; mf < 4; ++mf) {
      int la = laBase + mf * 16;
      af[mf][0] = *(const bf16x8*)&sA[p][0][la][cgr0];
      af[mf][1] = *(const bf16x8*)&sA[p][0][la][cgr1];
    }
#pragma unroll
    for (int nf = 0; nf < 2; ++nf) {
      int lb = lbBase + nf * 16;
      bfv[nf][0] = *(const bf16x8*)&sB[p][lb][cgr0];
      bfv[nf][1] = *(const bf16x8*)&sB[p][lb][cgr1];
    }
    if (pf) {
      stageA(p ^ 1, 0, kt + 1);
      stageB(p ^ 1, kt + 1);
    }
    __builtin_amdgcn_s_setprio(1);
#pragma unroll
    for (int mf = 0; mf < 4; ++mf)
#pragma unroll
      for (int nf = 0; nf < 2; ++nf) {
        acc[mf][nf] = MFMA16(af[mf][0], bfv[nf][0], acc[mf][nf]);
        acc[mf][nf] = MFMA16(af[mf][1], bfv[nf][1], acc[mf][nf]);
      }
    __builtin_amdgcn_s_setprio(0);
    // ======== Ph1: quadrants (1,*). Needs A1 (af overwrite). ========
    if (pf) { VMWAIT(3); } else { VMWAIT(0); }  // lands A1 of kt
    BAR();
#pragma unroll
    for (int mf = 0; mf < 4; ++mf) {
      int la = laBase + mf * 16;
      af[mf][0] = *(const bf16x8*)&sA[p][1][la][cgr0];
      af[mf][1] = *(const bf16x8*)&sA[p][1][la][cgr1];
    }
    if (pf) stageA(p ^ 1, 1, kt + 1);
    __builtin_amdgcn_s_setprio(1);
#pragma unroll
    for (int mf = 0; mf < 4; ++mf)
#pragma unroll
      for (int nf = 0; nf < 2; ++nf) {
        acc[4 + mf][nf] = MFMA16(af[mf][0], bfv[nf][0], acc[4 + mf][nf]);
        acc[4 + mf][nf] = MFMA16(af[mf][1], bfv[nf][1], acc[4 + mf][nf]);
      }
    __builtin_amdgcn_s_setprio(0);
  };

  int p = 0;
  for (int kt = 0; kt < KT - 1; ++kt) {
    ktile(kt, p, true);
    p ^= 1;
  }
  ktile(KT - 1, p, false);  // peeled: no prefetch; waits 1/0

  // ---- epilogue: +bias, optional GELU, bf16 store.
  // C/D mapping (m89): col = lane&15, row = (lane>>4)*4 + r.
  const float* be = bias + (size_t)e * N + bn * BN;
  __hip_bfloat16* oe =
      out + (size_t)e * T_ * N + (size_t)(bm * 256) * N + bn * BN;
  int r4 = l16h * 4;
#pragma unroll
  for (int mi = 0; mi < 8; ++mi) {
    int mh = mi >> 2, mf = mi & 3;
    int rowb = wr * 128 + mh * 64 + mf * 16 + r4;
#pragma unroll
    for (int nf = 0; nf < 2; ++nf) {
      int cc   = wc * 32 + nf * 16 + l15;
      float bv = be[cc];
#pragma unroll
      for (int r = 0; r < 4; ++r) {
        float v = acc[mi][nf][r] + bv;
        if (GELU) v = gelu_fast(v);
        oe[(size_t)(rowb + r) * N + cc] = __float2bfloat16(v);
      }
    }
  }
}

// ---------------------------------------------------------------------------
// Grouped GEMM, round-10 config (GEMM2, frozen: measured ~82us at KT=48):
// 256x192 tile, BK=64, 768 thr = 12 waves (2M x 6N), per-wave 128x32,
// 3 waves/SIMD. See round-10 header for the ledger.
// ---------------------------------------------------------------------------
template <int K, int N, bool GELU>
__global__ __launch_bounds__(768, 3) void gemm12w_kernel(
    const __hip_bfloat16* __restrict__ A,
    const __hip_bfloat16* __restrict__ B,
    const float* __restrict__ bias,
    __hip_bfloat16* __restrict__ out) {
  constexpr int BN = 192;
  constexpr int MT = T_ / 256;
  constexpr int NT = N / BN;
  constexpr int KT = K / 64;

  __shared__ __hip_bfloat16 sA[2][2][128][64];  // 65536 B
  __shared__ __hip_bfloat16 sB[2][BN][64];      // 49152 B

  int nwg = gridDim.x;
  int b0  = blockIdx.x;
  int bid = (b0 & 7) * (nwg >> 3) + (b0 >> 3);

  int e   = bid / (MT * NT);
  int rr_ = bid % (MT * NT);
  int bm  = rr_ / NT;
  int bn  = rr_ % NT;

  const __hip_bfloat16* Ae = A + (size_t)e * T_ * K + (size_t)bm * 256 * K;
  const __hip_bfloat16* Be = B + (size_t)e * N  * K + (size_t)bn * BN * K;

  int tid  = threadIdx.x;
  int lane = tid & 63;
  int wid  = tid >> 6;      // 0..11
  int wr   = wid / 6;       // 0..1 (M)
  int wc   = wid % 6;       // 0..5 (N)
  int l15  = lane & 15;
  int l16h = lane >> 4;     // 0..3
  bool isX = (tid < 512);   // wave-uniform staging class

  int i0 = tid, i1 = 512 + tid;
  int lr0 = i0 >> 3, c80 = i0 & 7, cg0 = c80 ^ (lr0 & 7);
  int lr1 = i1 >> 3, c81 = i1 & 7, cg1 = c81 ^ (lr1 & 7);
  int rA0 = ((lr0 >> 6) << 7) | (lr0 & 63);
  int rA1 = ((lr1 >> 6) << 7) | (lr1 & 63);
  const size_t oA0 = (size_t)rA0 * K + cg0 * 8;
  const size_t oA1 = (size_t)rA1 * K + cg1 * 8;
  const size_t HOFF = (size_t)64 * K;
  size_t oB[2];
  int    dB[2];
#pragma unroll
  for (int q = 0; q < 2; ++q) {
    int idx = q * 768 + tid;
    int lr = idx >> 3, c8 = idx & 7;
    int cg = c8 ^ (lr & 7);
    oB[q] = (size_t)lr * K + cg * 8;
    dB[q] = lr * 64 + c8 * 8;
  }

  auto stageA = [&](int buf, int h, int kt) {
    if (isX) {
      const __hip_bfloat16* g = Ae + (size_t)kt * 64 + (size_t)h * HOFF;
      gload16(g + oA0, &sA[buf][h][lr0][c80 * 8]);
      gload16(g + oA1, &sA[buf][h][lr1][c81 * 8]);
    }
  };
  auto stageB = [&](int buf, int kt) {
    const __hip_bfloat16* g = Be + (size_t)kt * 64;
    __hip_bfloat16* l = &sB[buf][0][0];
    gload16(g + oB[0], l + dB[0]);
    gload16(g + oB[1], l + dB[1]);
  };

  int laBase = wr * 64 + l15;
  int lbBase = wc * 32 + l15;
  int s7   = l15 & 7;
  int cgr0 = ((0 | l16h) ^ s7) * 8;
  int cgr1 = ((4 | l16h) ^ s7) * 8;

  f32x4 acc[8][2] = {};
  bf16x8 af[4][2], bfv[2][2];

  stageA(0, 0, 0);
  stageB(0, 0);
  stageA(0, 1, 0);

  auto ktile = [&](int kt, int p, bool pf) {
    if (isX) { VMWAIT(2); } else { VMWAIT(0); }
    BAR();
#pragma unroll
    for (int mf = 0; mf < 4; ++mf) {
      int la = laBase + mf * 16;
      af[mf][0] = *(const bf16x8*)&sA[p][0][la][cgr0];
      af[mf][1] = *(const bf16x8*)&sA[p][0][la][cgr1];
    }
#pragma unroll
    for (int nf = 0; nf < 2; ++nf) {
      int lb = lbBase + nf * 16;
      bfv[nf][0] = *(const bf16x8*)&sB[p][lb][cgr0];
      bfv[nf][1] = *(const bf16x8*)&sB[p][lb][cgr1];
    }
    if (pf) {
      stageA(p ^ 1, 0, kt + 1);
      stageB(p ^ 1, kt + 1);
    }
    __builtin_amdgcn_s_setprio(1);
#pragma unroll
    for (int mf = 0; mf < 4; ++mf)
#pragma unroll
      for (int nf = 0; nf < 2; ++nf) {
        acc[mf][nf] = MFMA16(af[mf][0], bfv[nf][0], acc[mf][nf]);
        acc[mf][nf] = MFMA16(af[mf][1], bfv[nf][1], acc[mf][nf]);
      }
    __builtin_amdgcn_s_setprio(0);
    if (pf) {
      if (isX) { VMWAIT(4); }
    } else {
      if (isX) { VMWAIT(0); }
    }
    BAR();
#pragma unroll
    for (int mf = 0; mf < 4; ++mf) {
      int la = laBase + mf * 16;
      af[mf][0] = *(const bf16x8*)&sA[p][1][la][cgr0];
      af[mf][1] = *(const bf16x8*)&sA[p][1][la][cgr1];
    }
    if (pf) stageA(p ^ 1, 1, kt + 1);
    __builtin_amdgcn_s_setprio(1);
#pragma unroll
    for (int mf = 0; mf < 4; ++mf)
#pragma unroll
      for (int nf = 0; nf < 2; ++nf) {
        acc[4 + mf][nf] = MFMA16(af[mf][0], bfv[nf][0], acc[4 + mf][nf]);
        acc[4 + mf][nf] = MFMA16(af[mf][1], bfv[nf][1], acc[4 + mf][nf]);
      }
    __builtin_amdgcn_s_setprio(0);
  };

  int p = 0;
  for (int kt = 0; kt < KT - 1; ++kt) {
    ktile(kt, p, true);
    p ^= 1;
  }
  ktile(KT - 1, p, false);

  const float* be = bias + (size_t)e * N + bn * BN;
  __hip_bfloat16* oe =
      out + (size_t)e * T_ * N + (size_t)(bm * 256) * N + bn * BN;
  int r4 = l16h * 4;
#pragma unroll
  for (int mi = 0; mi < 8; ++mi) {
    int mh = mi >> 2, mf = mi & 3;
    int rowb = wr * 128 + mh * 64 + mf * 16 + r4;
#pragma unroll
    for (int nf = 0; nf < 2; ++nf) {
      int cc   = wc * 32 + nf * 16 + l15;
      float bv = be[cc];
#pragma unroll
      for (int r = 0; r < 4; ++r) {
        float v = acc[mi][nf][r] + bv;
        if (GELU) v = gelu_fast(v);
        oe[(size_t)(rowb + r) * N + cc] = __float2bfloat16(v);
      }
    }
  }
}

// ---------------------------------------------------------------------------
// Residual + LayerNorm, vectorized (round-8, frozen): 384 thr/row, ushort2
// loads of yraw and x_bf; float2 stores.
// ---------------------------------------------------------------------------
__global__ __launch_bounds__(384) void ln_kernel(
    const __hip_bfloat16* __restrict__ yraw,
    const __hip_bfloat16* __restrict__ xbf,
    const float* __restrict__ gamma, const float* __restrict__ beta,
    float* __restrict__ out) {
  int row  = blockIdx.x;
  int tid  = threadIdx.x;
  int lane = tid & 63, wid = tid >> 6;  // 6 waves
  int c    = tid * 2;
  const __hip_bfloat16* yr = yraw + (size_t)row * H_;
  const __hip_bfloat16* xr = xbf + (size_t)row * H_;

  ushort2 ya = *(const ushort2*)&yr[c];
  ushort2 xa = *(const ushort2*)&xr[c];
  __hip_bfloat16 t;
  float v0, v1;
  *(ushort*)&t = ya.x; v0 = __bfloat162float(t);
  *(ushort*)&t = xa.x; v0 += __bfloat162float(t);
  *(ushort*)&t = ya.y; v1 = __bfloat162float(t);
  *(ushort*)&t = xa.y; v1 += __bfloat162float(t);

  float s = v0 + v1, s2 = v0 * v0 + v1 * v1;
#pragma unroll
  for (int o = 32; o > 0; o >>= 1) {
    s  += __shfl_down(s, o);
    s2 += __shfl_down(s2, o);
  }
  __shared__ float ls[6], ls2[6];
  if (lane == 0) { ls[wid] = s; ls2[wid] = s2; }
  __syncthreads();
  float tot  = ls[0] + ls[1] + ls[2] + ls[3] + ls[4] + ls[5];
  float tot2 = ls2[0] + ls2[1] + ls2[2] + ls2[3] + ls2[4] + ls2[5];
  float mean = tot * (1.0f / 768.0f);
  float var  = tot2 * (1.0f / 768.0f) - mean * mean;
  float inv  = rsqrtf(var + 1e-12f);
  float2 g = *(const float2*)&gamma[c];
  float2 b = *(const float2*)&beta[c];
  float2 o2;
  o2.x = (v0 - mean) * inv * g.x + b.x;
  o2.y = (v1 - mean) * inv * g.y + b.y;
  *(float2*)&out[(size_t)row * H_ + c] = o2;
}

// ---------------------------------------------------------------------------
extern "C" void kernel_launch(void* const* d_in, const int* in_sizes, int n_in,
                              void* d_out, int out_size, void* d_ws,
                              size_t ws_size, hipStream_t stream) {
  const float* x     = (const float*)d_in[0];  // [N, H]
  const float* w1    = (const float*)d_in[1];  // [E, H, I]
  const float* b1    = (const float*)d_in[2];  // [E, I]
  const float* w2    = (const float*)d_in[3];  // [E, I, H]
  const float* b2    = (const float*)d_in[4];  // [E, H]
  const float* gamma = (const float*)d_in[5];  // [H]
  const float* beta  = (const float*)d_in[6];  // [H]
  float* out = (float*)d_out;

  // Workspace layout (192 MiB, exactly full):
  //   w1t  [E][I][H] bf16 @ 0           (37,748,736 B; DEAD after GEMM1 ->
  //                                      yraw [N][H] bf16 aliases @0)
  //   w2t  [E][H][I] bf16 @ 37748736    (37,748,736 B)
  //   x_bf [N][H]    bf16 @ 75497472    (25,165,824 B; live until LN)
  //   inter[E][T][I] bf16 @ 100663296   (100,663,296 B)
  char* ws = (char*)d_ws;
  __hip_bfloat16* w1t   = (__hip_bfloat16*)(ws);
  __hip_bfloat16* w2t   = (__hip_bfloat16*)(ws + 37748736);
  __hip_bfloat16* x_bf  = (__hip_bfloat16*)(ws + 75497472);
  __hip_bfloat16* inter = (__hip_bfloat16*)(ws + 100663296);
  __hip_bfloat16* yraw  = (__hip_bfloat16*)(ws);  // w1t dead after GEMM1

  // fused prep: cvt + w1T + w2T in one launch
  prep_kernel<<<CVT_BLOCKS + 2 * WT_BLOCKS, 256, 0, stream>>>(
      x, x_bf, w1, w1t, w2, w2t);
  // GEMM1 + bias + GELU -> inter : 16-wave 256x256, 8*8*12 = 768 blocks
  gemm16w_kernel<H_, I_, true>
      <<<E_ * (T_ / 256) * (I_ / 256), 1024, 0, stream>>>(x_bf, w1t, b1, inter);
  // GEMM2 + bias -> yraw : 12-wave 256x192 (r10 measured), 256 blocks
  gemm12w_kernel<I_, H_, false>
      <<<E_ * (T_ / 256) * (H_ / 192), 768, 0, stream>>>(inter, w2t, b2, yraw);
  // residual + LayerNorm -> out (fp32); residual read as bf16 (x_bf)
  ln_kernel<<<NTOK, 384, 0, stream>>>(yraw, x_bf, gamma, beta, out);
}

// Round 12
// 239.116 us; speedup vs baseline: 1.0689x; 1.0689x over previous
//
#include <hip/hip_runtime.h>
#include <hip/hip_bf16.h>
#include <math.h>

// Problem dims (fixed by setup_inputs)
#define E_   8
#define H_   768
#define I_   3072
#define T_   2048
#define NTOK (E_ * T_)

typedef __attribute__((ext_vector_type(8))) short bf16x8;   // 8 bf16 = 4 VGPRs
typedef __attribute__((ext_vector_type(4))) float f32x4;    // MFMA accum

typedef __attribute__((address_space(3))) void lds_void;
typedef const __attribute__((address_space(1))) void gl_void;

__device__ __forceinline__ void gload16(const void* g, void* l) {
  // 16B async global->LDS. LDS dest is wave-uniform base + lane*16.
  __builtin_amdgcn_global_load_lds((gl_void*)g, (lds_void*)l, 16, 0, 0);
}

// Compiler-only fence (0 instructions) + raw HW barrier. NOT __syncthreads():
// that would emit s_waitcnt vmcnt(0) and drain the prefetch pipeline (T4).
#define FENCE() asm volatile("" ::: "memory")
#define BAR()                         \
  do {                                \
    FENCE();                          \
    __builtin_amdgcn_s_barrier();     \
    FENCE();                          \
  } while (0)
#define VMWAIT(n) asm volatile("s_waitcnt vmcnt(" #n ")" ::: "memory")

#define MFMA16(a, b, c) __builtin_amdgcn_mfma_f32_16x16x32_bf16(a, b, c, 0, 0, 0)

// Fast GELU: v * sigmoid(1.5957691*(v + 0.044715 v^3)); |err| ~3e-4 << bf16
// storage error of the intermediate. (Round-2 verified, absmax 0.031.)
__device__ __forceinline__ float gelu_fast(float v) {
  float inner = v * fmaf(v * v, 0.044715f, 1.0f);
  float e = __builtin_amdgcn_exp2f(inner * -2.3022082f);
  return v * __builtin_amdgcn_rcpf(1.0f + e);
}

// ---------------------------------------------------------------------------
// Fused prep kernel (round-9, frozen; ~30us, runs at L3 speed):
//   blocks [0, 12288)        : x fp32 -> x_bf bf16 (float4 / ushort4)
//   blocks [12288, 16896)    : w1 [E][H][I] -> w1t [E][I][H] bf16
//   blocks [16896, 21504)    : w2 [E][I][H] -> w2t [E][H][I] bf16
// ---------------------------------------------------------------------------
#define CVT_BLOCKS 12288         // NTOK*H / (256*4)
#define WT_BLOCKS  4608          // (I/64)*(H/64)*E = 48*12*8

__global__ __launch_bounds__(256) void prep_kernel(
    const float* __restrict__ x, __hip_bfloat16* __restrict__ x_bf,
    const float* __restrict__ w1, __hip_bfloat16* __restrict__ w1t,
    const float* __restrict__ w2, __hip_bfloat16* __restrict__ w2t) {
  __shared__ __hip_bfloat16 tile[64][66];
  int b = blockIdx.x;

  if (b < CVT_BLOCKS) {  // ---- cvt branch
    int i = (b * 256 + threadIdx.x) * 4;
    float4 v = *(const float4*)(x + i);
    __align__(8) __hip_bfloat16 t[4];
    t[0] = __float2bfloat16(v.x);
    t[1] = __float2bfloat16(v.y);
    t[2] = __float2bfloat16(v.z);
    t[3] = __float2bfloat16(v.w);
    *(ushort4*)(x_bf + i) = *(const ushort4*)t;
    return;
  }

  // ---- transpose branches: [E][R][C] fp32 -> [E][C][R] bf16
  const float* src;
  __hip_bfloat16* dst;
  int R, C, c0, r0;
  if (b < CVT_BLOCKS + WT_BLOCKS) {
    int t = b - CVT_BLOCKS;
    int e = t / 576, rem = t % 576;       // 576 = (I/64)*(H/64)
    R = H_; C = I_;                       // src w1 [H][I]
    c0 = (rem % 48) * 64;
    r0 = (rem / 48) * 64;
    src = w1 + (size_t)e * R * C;
    dst = w1t + (size_t)e * R * C;
  } else {
    int t = b - (CVT_BLOCKS + WT_BLOCKS);
    int e = t / 576, rem = t % 576;
    R = I_; C = H_;                       // src w2 [I][H]
    c0 = (rem % 12) * 64;
    r0 = (rem / 12) * 64;
    src = w2 + (size_t)e * R * C;
    dst = w2t + (size_t)e * R * C;
  }

  int tx = threadIdx.x & 31;  // col-pair index (2 cols/thread)
  int ty = threadIdx.x >> 5;  // 8 rows/pass
#pragma unroll
  for (int r = ty; r < 64; r += 8) {
    float2 v = *(const float2*)&src[(size_t)(r0 + r) * C + c0 + 2 * tx];
    __hip_bfloat16 b0 = __float2bfloat16(v.x);
    __hip_bfloat16 b1 = __float2bfloat16(v.y);
    ushort2 w;
    w.x = *(const ushort*)&b0;
    w.y = *(const ushort*)&b1;
    *(ushort2*)&tile[r][2 * tx] = w;
  }
  __syncthreads();
#pragma unroll
  for (int rr = ty; rr < 64; rr += 8) {
    ushort2 v;
    v.x = *(const ushort*)&tile[2 * tx][rr];
    v.y = *(const ushort*)&tile[2 * tx + 1][rr];
    *(ushort2*)&dst[(size_t)(c0 + rr) * R + r0 + 2 * tx] = v;
  }
}

// ---------------------------------------------------------------------------
// GEMM1 config (measured best for short K=768: 96.6us, r8/r9): 256x256
// tile, BK=64, 512 thr = 8 waves (2M x 4N), per-wave 128x64 out.
// 2-phase merged schedule; counted vmcnt; T1+T2 swizzles. Occupancy probes
// r10/r11 (12w/16w thin-wave variants) both regressed at this K — 8-wave
// wide-tile wins on fetch locality + per-phase MFMA density.
// ---------------------------------------------------------------------------
template <int K, int N, int BN, bool GELU>
__global__ __launch_bounds__(512, 2) void gemm2p_kernel(
    const __hip_bfloat16* __restrict__ A,
    const __hip_bfloat16* __restrict__ B,
    const float* __restrict__ bias,
    __hip_bfloat16* __restrict__ out) {
  constexpr int MT = T_ / 256;
  constexpr int NT = N / BN;
  constexpr int KT = K / 64;
  constexpr int NF = BN / 64;     // B frags per wave
  constexpr int WCW = BN / 4;     // per-wave col width
  constexpr int BPASS = BN / 64;  // B stage passes

  __shared__ __hip_bfloat16 sA[2][2][128][64];
  __shared__ __hip_bfloat16 sB[2][BN][64];

  // T1: bijective XCD swizzle (gridDim.x % 8 == 0).
  int nwg = gridDim.x;
  int b0  = blockIdx.x;
  int bid = (b0 & 7) * (nwg >> 3) + (b0 >> 3);

  int e   = bid / (MT * NT);
  int rr_ = bid % (MT * NT);
  int bm  = rr_ / NT;
  int bn  = rr_ % NT;

  const __hip_bfloat16* Ae = A + (size_t)e * T_ * K + (size_t)bm * 256 * K;
  const __hip_bfloat16* Be = B + (size_t)e * N  * K + (size_t)bn * BN * K;

  int tid  = threadIdx.x;
  int lane = tid & 63;
  int wid  = tid >> 6;
  int wr   = wid >> 2;   // 0..1 (M)
  int wc   = wid & 3;    // 0..3 (N)
  int l15  = lane & 15;
  int l16h = lane >> 4;  // 0..3

  // --- staging geometry, hoisted (T2: source col-group pre-swizzled).
  int i0 = tid, i1 = 512 + tid;
  int lr0 = i0 >> 3, c80 = i0 & 7, cg0 = c80 ^ (lr0 & 7);
  int lr1 = i1 >> 3, c81 = i1 & 7, cg1 = c81 ^ (lr1 & 7);
  int rA0 = ((lr0 >> 6) << 7) | (lr0 & 63);  // + h*64
  int rA1 = ((lr1 >> 6) << 7) | (lr1 & 63);
  const size_t oA0 = (size_t)rA0 * K + cg0 * 8;
  const size_t oA1 = (size_t)rA1 * K + cg1 * 8;
  const size_t HOFF = (size_t)64 * K;
  size_t oB[BPASS];
  int    dB[BPASS];
#pragma unroll
  for (int q = 0; q < BPASS; ++q) {
    int idx = q * 512 + tid;
    int lr = idx >> 3, c8 = idx & 7;
    int cg = c8 ^ (lr & 7);
    oB[q] = (size_t)lr * K + cg * 8;
    dB[q] = lr * 64 + c8 * 8;
  }

  auto stageA = [&](int buf, int h, int kt) {
    const __hip_bfloat16* g = Ae + (size_t)kt * 64 + (size_t)h * HOFF;
    gload16(g + oA0, &sA[buf][h][lr0][c80 * 8]);
    gload16(g + oA1, &sA[buf][h][lr1][c81 * 8]);
  };
  auto stageB = [&](int buf, int kt) {
    const __hip_bfloat16* g = Be + (size_t)kt * 64;
    __hip_bfloat16* l = &sB[buf][0][0];
#pragma unroll
    for (int q = 0; q < BPASS; ++q) gload16(g + oB[q], l + dB[q]);
  };

  // --- fragment-read geometry (T2 read-side XOR)
  int laBase = wr * 64 + l15;
  int lbBase = wc * WCW + l15;
  int s7   = l15 & 7;
  int cgr0 = ((0 | l16h) ^ s7) * 8;
  int cgr1 = ((4 | l16h) ^ s7) * 8;

  f32x4 acc[8][NF] = {};
  bf16x8 af[4][2], bfv[NF][2];

  // ---- prologue: stage tile 0 in FIFO order A0, B, A1.
  stageA(0, 0, 0);
  stageB(0, 0);
  stageA(0, 1, 0);

  auto ktile = [&](int kt, int p, bool pf) {
    // ======== Ph0: quadrants (0,*). Needs A0 + all B. ========
    VMWAIT(2);  // lands A0,B of kt (leaves A1's 2)
    BAR();
#pragma unroll
    for (int mf = 0; mf < 4; ++mf) {
      int la = laBase + mf * 16;
      af[mf][0] = *(const bf16x8*)&sA[p][0][la][cgr0];
      af[mf][1] = *(const bf16x8*)&sA[p][0][la][cgr1];
    }
#pragma unroll
    for (int nf = 0; nf < NF; ++nf) {
      int lb = lbBase + nf * 16;
      bfv[nf][0] = *(const bf16x8*)&sB[p][lb][cgr0];
      bfv[nf][1] = *(const bf16x8*)&sB[p][lb][cgr1];
    }
    if (pf) {
      stageA(p ^ 1, 0, kt + 1);
      stageB(p ^ 1, kt + 1);
    }
    __builtin_amdgcn_s_setprio(1);
#pragma unroll
    for (int mf = 0; mf < 4; ++mf)
#pragma unroll
      for (int nf = 0; nf < NF; ++nf) {
        acc[mf][nf] = MFMA16(af[mf][0], bfv[nf][0], acc[mf][nf]);
        acc[mf][nf] = MFMA16(af[mf][1], bfv[nf][1], acc[mf][nf]);
      }
    __builtin_amdgcn_s_setprio(0);
    // ======== Ph1: quadrants (1,*). Needs A1 (af overwrite). ========
    if (pf) {
      if constexpr (BN == 256) { VMWAIT(6); } else { VMWAIT(5); }
    } else {
      VMWAIT(0);
    }
    BAR();
#pragma unroll
    for (int mf = 0; mf < 4; ++mf) {
      int la = laBase + mf * 16;
      af[mf][0] = *(const bf16x8*)&sA[p][1][la][cgr0];
      af[mf][1] = *(const bf16x8*)&sA[p][1][la][cgr1];
    }
    if (pf) stageA(p ^ 1, 1, kt + 1);
    __builtin_amdgcn_s_setprio(1);
#pragma unroll
    for (int mf = 0; mf < 4; ++mf)
#pragma unroll
      for (int nf = 0; nf < NF; ++nf) {
        acc[4 + mf][nf] = MFMA16(af[mf][0], bfv[nf][0], acc[4 + mf][nf]);
        acc[4 + mf][nf] = MFMA16(af[mf][1], bfv[nf][1], acc[4 + mf][nf]);
      }
    __builtin_amdgcn_s_setprio(0);
  };

  int p = 0;
  for (int kt = 0; kt < KT - 1; ++kt) {
    ktile(kt, p, true);
    p ^= 1;
  }
  ktile(KT - 1, p, false);  // peeled: no prefetch; waits 2/0

  // ---- epilogue: +bias, optional GELU, bf16 store.
  // C/D mapping (m89): col = lane&15, row = (lane>>4)*4 + r.
  const float* be = bias + (size_t)e * N + bn * BN;
  __hip_bfloat16* oe =
      out + (size_t)e * T_ * N + (size_t)(bm * 256) * N + bn * BN;
  int r4 = l16h * 4;
#pragma unroll
  for (int mi = 0; mi < 8; ++mi) {
    int mh = mi >> 2, mf = mi & 3;
    int rowb = wr * 128 + mh * 64 + mf * 16 + r4;
#pragma unroll
    for (int nf = 0; nf < NF; ++nf) {
      int cc   = wc * WCW + nf * 16 + l15;
      float bv = be[cc];
#pragma unroll
      for (int r = 0; r < 4; ++r) {
        float v = acc[mi][nf][r] + bv;
        if (GELU) v = gelu_fast(v);
        oe[(size_t)(rowb + r) * N + cc] = __float2bfloat16(v);
      }
    }
  }
}

// ---------------------------------------------------------------------------
// GEMM2 config (measured best for long K=3072: ~81us, r10): 256x192 tile,
// BK=64, 768 thr = 12 waves (2M x 6N), per-wave 128x32 -> 3 waves/SIMD.
// Staging: A by waves 0-7 (class X), B by all 12 waves; per-class counted
// vmcnt ledger (see r10 header). T1+T2 swizzles.
// ---------------------------------------------------------------------------
template <int K, int N, bool GELU>
__global__ __launch_bounds__(768, 3) void gemm12w_kernel(
    const __hip_bfloat16* __restrict__ A,
    const __hip_bfloat16* __restrict__ B,
    const float* __restrict__ bias,
    __hip_bfloat16* __restrict__ out) {
  constexpr int BN = 192;
  constexpr int MT = T_ / 256;
  constexpr int NT = N / BN;
  constexpr int KT = K / 64;

  __shared__ __hip_bfloat16 sA[2][2][128][64];  // 65536 B
  __shared__ __hip_bfloat16 sB[2][BN][64];      // 49152 B

  int nwg = gridDim.x;
  int b0  = blockIdx.x;
  int bid = (b0 & 7) * (nwg >> 3) + (b0 >> 3);

  int e   = bid / (MT * NT);
  int rr_ = bid % (MT * NT);
  int bm  = rr_ / NT;
  int bn  = rr_ % NT;

  const __hip_bfloat16* Ae = A + (size_t)e * T_ * K + (size_t)bm * 256 * K;
  const __hip_bfloat16* Be = B + (size_t)e * N  * K + (size_t)bn * BN * K;

  int tid  = threadIdx.x;
  int lane = tid & 63;
  int wid  = tid >> 6;      // 0..11
  int wr   = wid / 6;       // 0..1 (M)
  int wc   = wid % 6;       // 0..5 (N)
  int l15  = lane & 15;
  int l16h = lane >> 4;     // 0..3
  bool isX = (tid < 512);   // wave-uniform staging class

  int i0 = tid, i1 = 512 + tid;
  int lr0 = i0 >> 3, c80 = i0 & 7, cg0 = c80 ^ (lr0 & 7);
  int lr1 = i1 >> 3, c81 = i1 & 7, cg1 = c81 ^ (lr1 & 7);
  int rA0 = ((lr0 >> 6) << 7) | (lr0 & 63);
  int rA1 = ((lr1 >> 6) << 7) | (lr1 & 63);
  const size_t oA0 = (size_t)rA0 * K + cg0 * 8;
  const size_t oA1 = (size_t)rA1 * K + cg1 * 8;
  const size_t HOFF = (size_t)64 * K;
  size_t oB[2];
  int    dB[2];
#pragma unroll
  for (int q = 0; q < 2; ++q) {
    int idx = q * 768 + tid;
    int lr = idx >> 3, c8 = idx & 7;
    int cg = c8 ^ (lr & 7);
    oB[q] = (size_t)lr * K + cg * 8;
    dB[q] = lr * 64 + c8 * 8;
  }

  auto stageA = [&](int buf, int h, int kt) {
    if (isX) {
      const __hip_bfloat16* g = Ae + (size_t)kt * 64 + (size_t)h * HOFF;
      gload16(g + oA0, &sA[buf][h][lr0][c80 * 8]);
      gload16(g + oA1, &sA[buf][h][lr1][c81 * 8]);
    }
  };
  auto stageB = [&](int buf, int kt) {
    const __hip_bfloat16* g = Be + (size_t)kt * 64;
    __hip_bfloat16* l = &sB[buf][0][0];
    gload16(g + oB[0], l + dB[0]);
    gload16(g + oB[1], l + dB[1]);
  };

  int laBase = wr * 64 + l15;
  int lbBase = wc * 32 + l15;
  int s7   = l15 & 7;
  int cgr0 = ((0 | l16h) ^ s7) * 8;
  int cgr1 = ((4 | l16h) ^ s7) * 8;

  f32x4 acc[8][2] = {};
  bf16x8 af[4][2], bfv[2][2];

  stageA(0, 0, 0);
  stageB(0, 0);
  stageA(0, 1, 0);

  auto ktile = [&](int kt, int p, bool pf) {
    if (isX) { VMWAIT(2); } else { VMWAIT(0); }
    BAR();
#pragma unroll
    for (int mf = 0; mf < 4; ++mf) {
      int la = laBase + mf * 16;
      af[mf][0] = *(const bf16x8*)&sA[p][0][la][cgr0];
      af[mf][1] = *(const bf16x8*)&sA[p][0][la][cgr1];
    }
#pragma unroll
    for (int nf = 0; nf < 2; ++nf) {
      int lb = lbBase + nf * 16;
      bfv[nf][0] = *(const bf16x8*)&sB[p][lb][cgr0];
      bfv[nf][1] = *(const bf16x8*)&sB[p][lb][cgr1];
    }
    if (pf) {
      stageA(p ^ 1, 0, kt + 1);
      stageB(p ^ 1, kt + 1);
    }
    __builtin_amdgcn_s_setprio(1);
#pragma unroll
    for (int mf = 0; mf < 4; ++mf)
#pragma unroll
      for (int nf = 0; nf < 2; ++nf) {
        acc[mf][nf] = MFMA16(af[mf][0], bfv[nf][0], acc[mf][nf]);
        acc[mf][nf] = MFMA16(af[mf][1], bfv[nf][1], acc[mf][nf]);
      }
    __builtin_amdgcn_s_setprio(0);
    if (pf) {
      if (isX) { VMWAIT(4); }
    } else {
      if (isX) { VMWAIT(0); }
    }
    BAR();
#pragma unroll
    for (int mf = 0; mf < 4; ++mf) {
      int la = laBase + mf * 16;
      af[mf][0] = *(const bf16x8*)&sA[p][1][la][cgr0];
      af[mf][1] = *(const bf16x8*)&sA[p][1][la][cgr1];
    }
    if (pf) stageA(p ^ 1, 1, kt + 1);
    __builtin_amdgcn_s_setprio(1);
#pragma unroll
    for (int mf = 0; mf < 4; ++mf)
#pragma unroll
      for (int nf = 0; nf < 2; ++nf) {
        acc[4 + mf][nf] = MFMA16(af[mf][0], bfv[nf][0], acc[4 + mf][nf]);
        acc[4 + mf][nf] = MFMA16(af[mf][1], bfv[nf][1], acc[4 + mf][nf]);
      }
    __builtin_amdgcn_s_setprio(0);
  };

  int p = 0;
  for (int kt = 0; kt < KT - 1; ++kt) {
    ktile(kt, p, true);
    p ^= 1;
  }
  ktile(KT - 1, p, false);

  const float* be = bias + (size_t)e * N + bn * BN;
  __hip_bfloat16* oe =
      out + (size_t)e * T_ * N + (size_t)(bm * 256) * N + bn * BN;
  int r4 = l16h * 4;
#pragma unroll
  for (int mi = 0; mi < 8; ++mi) {
    int mh = mi >> 2, mf = mi & 3;
    int rowb = wr * 128 + mh * 64 + mf * 16 + r4;
#pragma unroll
    for (int nf = 0; nf < 2; ++nf) {
      int cc   = wc * 32 + nf * 16 + l15;
      float bv = be[cc];
#pragma unroll
      for (int r = 0; r < 4; ++r) {
        float v = acc[mi][nf][r] + bv;
        if (GELU) v = gelu_fast(v);
        oe[(size_t)(rowb + r) * N + cc] = __float2bfloat16(v);
      }
    }
  }
}

// ---------------------------------------------------------------------------
// Residual + LayerNorm, vectorized (round-8, frozen): 384 thr/row, ushort2
// loads of yraw and x_bf; float2 stores.
// ---------------------------------------------------------------------------
__global__ __launch_bounds__(384) void ln_kernel(
    const __hip_bfloat16* __restrict__ yraw,
    const __hip_bfloat16* __restrict__ xbf,
    const float* __restrict__ gamma, const float* __restrict__ beta,
    float* __restrict__ out) {
  int row  = blockIdx.x;
  int tid  = threadIdx.x;
  int lane = tid & 63, wid = tid >> 6;  // 6 waves
  int c    = tid * 2;
  const __hip_bfloat16* yr = yraw + (size_t)row * H_;
  const __hip_bfloat16* xr = xbf + (size_t)row * H_;

  ushort2 ya = *(const ushort2*)&yr[c];
  ushort2 xa = *(const ushort2*)&xr[c];
  __hip_bfloat16 t;
  float v0, v1;
  *(ushort*)&t = ya.x; v0 = __bfloat162float(t);
  *(ushort*)&t = xa.x; v0 += __bfloat162float(t);
  *(ushort*)&t = ya.y; v1 = __bfloat162float(t);
  *(ushort*)&t = xa.y; v1 += __bfloat162float(t);

  float s = v0 + v1, s2 = v0 * v0 + v1 * v1;
#pragma unroll
  for (int o = 32; o > 0; o >>= 1) {
    s  += __shfl_down(s, o);
    s2 += __shfl_down(s2, o);
  }
  __shared__ float ls[6], ls2[6];
  if (lane == 0) { ls[wid] = s; ls2[wid] = s2; }
  __syncthreads();
  float tot  = ls[0] + ls[1] + ls[2] + ls[3] + ls[4] + ls[5];
  float tot2 = ls2[0] + ls2[1] + ls2[2] + ls2[3] + ls2[4] + ls2[5];
  float mean = tot * (1.0f / 768.0f);
  float var  = tot2 * (1.0f / 768.0f) - mean * mean;
  float inv  = rsqrtf(var + 1e-12f);
  float2 g = *(const float2*)&gamma[c];
  float2 b = *(const float2*)&beta[c];
  float2 o2;
  o2.x = (v0 - mean) * inv * g.x + b.x;
  o2.y = (v1 - mean) * inv * g.y + b.y;
  *(float2*)&out[(size_t)row * H_ + c] = o2;
}

// ---------------------------------------------------------------------------
extern "C" void kernel_launch(void* const* d_in, const int* in_sizes, int n_in,
                              void* d_out, int out_size, void* d_ws,
                              size_t ws_size, hipStream_t stream) {
  const float* x     = (const float*)d_in[0];  // [N, H]
  const float* w1    = (const float*)d_in[1];  // [E, H, I]
  const float* b1    = (const float*)d_in[2];  // [E, I]
  const float* w2    = (const float*)d_in[3];  // [E, I, H]
  const float* b2    = (const float*)d_in[4];  // [E, H]
  const float* gamma = (const float*)d_in[5];  // [H]
  const float* beta  = (const float*)d_in[6];  // [H]
  float* out = (float*)d_out;

  // Workspace layout (192 MiB, exactly full):
  //   w1t  [E][I][H] bf16 @ 0           (37,748,736 B; DEAD after GEMM1 ->
  //                                      yraw [N][H] bf16 aliases @0)
  //   w2t  [E][H][I] bf16 @ 37748736    (37,748,736 B)
  //   x_bf [N][H]    bf16 @ 75497472    (25,165,824 B; live until LN)
  //   inter[E][T][I] bf16 @ 100663296   (100,663,296 B)
  char* ws = (char*)d_ws;
  __hip_bfloat16* w1t   = (__hip_bfloat16*)(ws);
  __hip_bfloat16* w2t   = (__hip_bfloat16*)(ws + 37748736);
  __hip_bfloat16* x_bf  = (__hip_bfloat16*)(ws + 75497472);
  __hip_bfloat16* inter = (__hip_bfloat16*)(ws + 100663296);
  __hip_bfloat16* yraw  = (__hip_bfloat16*)(ws);  // w1t dead after GEMM1

  // fused prep: cvt + w1T + w2T in one launch
  prep_kernel<<<CVT_BLOCKS + 2 * WT_BLOCKS, 256, 0, stream>>>(
      x, x_bf, w1, w1t, w2, w2t);
  // GEMM1 + bias + GELU -> inter : 8-wave 256x256 gemm2p (measured 96.6us)
  gemm2p_kernel<H_, I_, 256, true>
      <<<E_ * (T_ / 256) * (I_ / 256), 512, 0, stream>>>(x_bf, w1t, b1, inter);
  // GEMM2 + bias -> yraw : 12-wave 256x192 gemm12w (measured ~81us)
  gemm12w_kernel<I_, H_, false>
      <<<E_ * (T_ / 256) * (H_ / 192), 768, 0, stream>>>(inter, w2t, b2, yraw);
  // residual + LayerNorm -> out (fp32); residual read as bf16 (x_bf)
  ln_kernel<<<NTOK, 384, 0, stream>>>(yraw, x_bf, gamma, beta, out);
}